// Round 1
// baseline (4429.710 us; speedup 1.0000x reference)
//
#include <hip/hip_runtime.h>
#include <cmath>

#define B_ 2
#define T_ 1024
#define D_ 2048
#define NH 16
#define KH 8
#define HD 128
#define HID_ 8192
#define BT_ (B_*T_)
#define WIN 512

__device__ __forceinline__ float wave_sum(float v) {
  #pragma unroll
  for (int o = 32; o > 0; o >>= 1) v += __shfl_down(v, o, 64);
  return v;
}

// ---------- RMSNorm over D, optional residual add ----------
__global__ __launch_bounds__(256) void rmsnorm_k(
    const float* __restrict__ in, const float* __restrict__ scale,
    const float* __restrict__ res, float* __restrict__ out)
{
  const long row = blockIdx.x;
  const float* x = in + row * D_;
  float ss = 0.f;
  for (int c = threadIdx.x; c < D_; c += 256) { float v = x[c]; ss += v * v; }
  ss = wave_sum(ss);
  __shared__ float red[4];
  if ((threadIdx.x & 63) == 0) red[threadIdx.x >> 6] = ss;
  __syncthreads();
  const float tot = red[0] + red[1] + red[2] + red[3];
  const float rs = rsqrtf(tot * (1.0f / D_) + 1e-6f);
  float* o = out + row * D_;
  const float* r = res ? res + row * D_ : nullptr;
  for (int c = threadIdx.x; c < D_; c += 256) {
    float v = x[c] * rs * (1.0f + scale[c]);
    o[c] = r ? v + r[c] : v;
  }
}

// ---------- generic fp32 GEMM: C[M,N]=A[M,K]@B[K,N], tile 64x128, K-step 16 ----------
// batched via blockIdx.z with element strides sAz/sBz/sCz.
__global__ __launch_bounds__(256) void gemm_f32(
    const float* __restrict__ A, int lda, long sAz,
    const float* __restrict__ B, int ldb, long sBz,
    float* __restrict__ C, int ldc, long sCz, int Kdim)
{
  A += (long)blockIdx.z * sAz; B += (long)blockIdx.z * sBz; C += (long)blockIdx.z * sCz;
  const int m0 = blockIdx.x * 64, n0 = blockIdx.y * 128;
  __shared__ float As[16][68];    // A^T tile, padded (16B-aligned rows)
  __shared__ float Bs[16][132];
  const int tid = threadIdx.x;
  const int tx = tid & 15, ty = tid >> 4;
  float acc[4][8] = {};
  for (int k0 = 0; k0 < Kdim; k0 += 16) {
    #pragma unroll
    for (int i = 0; i < 4; i++) {
      int idx = tid + i * 256, r = idx >> 4, c = idx & 15;
      As[c][r] = A[(long)(m0 + r) * lda + k0 + c];
    }
    #pragma unroll
    for (int i = 0; i < 8; i++) {
      int idx = tid + i * 256, r = idx >> 7, c = idx & 127;
      Bs[r][c] = B[(long)(k0 + r) * ldb + n0 + c];
    }
    __syncthreads();
    #pragma unroll
    for (int kk = 0; kk < 16; kk++) {
      float a[4], b[8];
      #pragma unroll
      for (int i = 0; i < 4; i++) a[i] = As[kk][ty * 4 + i];
      #pragma unroll
      for (int j = 0; j < 8; j++) b[j] = Bs[kk][tx * 8 + j];
      #pragma unroll
      for (int i = 0; i < 4; i++)
        #pragma unroll
        for (int j = 0; j < 8; j++) acc[i][j] += a[i] * b[j];
    }
    __syncthreads();
  }
  #pragma unroll
  for (int i = 0; i < 4; i++)
    #pragma unroll
    for (int j = 0; j < 8; j++)
      C[(long)(m0 + ty * 4 + i) * ldc + n0 + tx * 8 + j] = acc[i][j];
}

// ---------- fused gate/up GEMM + tanh-GELU epilogue: act = gelu(A@Bg) * (A@Bu) ----------
__global__ __launch_bounds__(256) void gemm_gateup(
    const float* __restrict__ A, const float* __restrict__ Bg,
    const float* __restrict__ Bu, float* __restrict__ C)
{
  const int m0 = blockIdx.x * 64, n0 = blockIdx.y * 128;
  __shared__ float As[16][68];
  __shared__ float Bgs[16][132];
  __shared__ float Bus[16][132];
  const int tid = threadIdx.x;
  const int tx = tid & 15, ty = tid >> 4;
  float accg[4][8] = {}, accu[4][8] = {};
  for (int k0 = 0; k0 < D_; k0 += 16) {
    #pragma unroll
    for (int i = 0; i < 4; i++) {
      int idx = tid + i * 256, r = idx >> 4, c = idx & 15;
      As[c][r] = A[(long)(m0 + r) * D_ + k0 + c];
    }
    #pragma unroll
    for (int i = 0; i < 8; i++) {
      int idx = tid + i * 256, r = idx >> 7, c = idx & 127;
      Bgs[r][c] = Bg[(long)(k0 + r) * HID_ + n0 + c];
      Bus[r][c] = Bu[(long)(k0 + r) * HID_ + n0 + c];
    }
    __syncthreads();
    #pragma unroll
    for (int kk = 0; kk < 16; kk++) {
      float a[4], bg[8], bu[8];
      #pragma unroll
      for (int i = 0; i < 4; i++) a[i] = As[kk][ty * 4 + i];
      #pragma unroll
      for (int j = 0; j < 8; j++) { bg[j] = Bgs[kk][tx * 8 + j]; bu[j] = Bus[kk][tx * 8 + j]; }
      #pragma unroll
      for (int i = 0; i < 4; i++)
        #pragma unroll
        for (int j = 0; j < 8; j++) { accg[i][j] += a[i] * bg[j]; accu[i][j] += a[i] * bu[j]; }
    }
    __syncthreads();
  }
  #pragma unroll
  for (int i = 0; i < 4; i++)
    #pragma unroll
    for (int j = 0; j < 8; j++) {
      float g = accg[i][j];
      float gl = 0.5f * g * (1.0f + tanhf(0.7978845608028654f * (g + 0.044715f * g * g * g)));
      C[(long)(m0 + ty * 4 + i) * HID_ + n0 + tx * 8 + j] = gl * accu[i][j];
    }
}

// ---------- per-head RMSNorm + RoPE (+ q scaling) on q/k rows ----------
__global__ __launch_bounds__(128) void qk_rope_k(
    float* __restrict__ qb, float* __restrict__ kb,
    const float* __restrict__ qsc, const float* __restrict__ ksc,
    const int* __restrict__ segpos)
{
  const int row = blockIdx.x;        // 0..BT-1
  const int hs  = blockIdx.y;        // 0..NH+KH-1
  const bool isq = hs < NH;
  float* base = isq ? qb + ((long)row * NH + hs) * HD
                    : kb + ((long)row * KH + (hs - NH)) * HD;
  const float* sc = isq ? qsc : ksc;
  const int j = threadIdx.x;
  float v = base[j];
  float ss = v * v;
  #pragma unroll
  for (int o = 32; o > 0; o >>= 1) ss += __shfl_down(ss, o, 64);
  __shared__ float red[2];
  if ((j & 63) == 0) red[j >> 6] = ss;
  __syncthreads();
  const float rs = rsqrtf((red[0] + red[1]) * (1.0f / HD) + 1e-6f);
  __shared__ float tmp[HD];
  tmp[j] = v * rs * (1.0f + sc[j]);
  __syncthreads();
  const int jj = j & 63;
  const float ts = powf(10000.0f, (float)jj * (1.0f / 64.0f));
  const float ang = (float)segpos[row] / ts;
  float sn, cs;
  sincosf(ang, &sn, &cs);
  const float fi = tmp[jj], se = tmp[jj + 64];
  float outv = (j < 64) ? (fi * cs - se * sn) : (se * cs + fi * sn);
  if (isq) outv *= 0.08838834764831845f;   // 128^-0.5
  base[j] = outv;
}

// ---------- flash-style fp32 attention, causal + sliding window, soft-cap ----------
__global__ __launch_bounds__(256) void attn_k(
    const float* __restrict__ qb, const float* __restrict__ kb,
    const float* __restrict__ vb, float* __restrict__ enc)
{
  const int qt = blockIdx.x, n = blockIdx.y, bb = blockIdx.z;
  const int kh = n >> 1;            // G = NH/KH = 2
  const int q0 = qt * 32;
  __shared__ float Qs[32][HD + 1];
  __shared__ float Ks[32][HD + 1];
  __shared__ float Vs[32][HD + 1];
  __shared__ float Ps[32][33];
  __shared__ float m_s[32], l_s[32], al_s[32];
  const int tid = threadIdx.x;
  for (int idx = tid; idx < 32 * HD; idx += 256) {
    int r = idx >> 7, c = idx & (HD - 1);
    Qs[r][c] = qb[((long)(bb * T_ + q0 + r) * NH + n) * HD + c];
  }
  if (tid < 32) { m_s[tid] = -1e30f; l_s[tid] = 0.f; }
  float O[2][8] = {};
  const int sty = tid >> 4, stx = tid & 15;
  const int r0 = sty * 2, c0 = stx * 2;
  const int kt_lo = (q0 >= WIN) ? (q0 - (WIN - 1)) / 32 : 0;
  for (int kt = kt_lo; kt <= qt; kt++) {
    const int k0 = kt * 32;
    for (int idx = tid; idx < 32 * HD; idx += 256) {
      int r = idx >> 7, c = idx & (HD - 1);
      long g = ((long)(bb * T_ + k0 + r) * KH + kh) * HD + c;
      Ks[r][c] = kb[g];
      Vs[r][c] = vb[g];
    }
    __syncthreads();
    float s[2][2] = {};
    for (int kk = 0; kk < HD; kk++) {
      float a0 = Qs[r0][kk], a1 = Qs[r0 + 1][kk];
      float b0 = Ks[c0][kk], b1 = Ks[c0 + 1][kk];
      s[0][0] += a0 * b0; s[0][1] += a0 * b1;
      s[1][0] += a1 * b0; s[1][1] += a1 * b1;
    }
    #pragma unroll
    for (int i = 0; i < 2; i++) {
      const int qp = q0 + r0 + i;
      float sv[2]; bool vld[2];
      float rm = -1e30f;
      #pragma unroll
      for (int j = 0; j < 2; j++) {
        const int kp = k0 + c0 + j;
        float t = tanhf(s[i][j] * (1.0f / 50.0f)) * 50.0f;   // soft-cap
        bool ok = (kp <= qp) && (kp > qp - WIN);
        sv[j] = t; vld[j] = ok;
        if (ok) rm = fmaxf(rm, t);
      }
      #pragma unroll
      for (int m = 8; m >= 1; m >>= 1) rm = fmaxf(rm, __shfl_xor(rm, m, 64));
      const float mold = m_s[r0 + i];
      const float mnew = fmaxf(mold, rm);
      const float al = expf(mold - mnew);
      float psum = 0.f;
      #pragma unroll
      for (int j = 0; j < 2; j++) {
        float p = vld[j] ? expf(sv[j] - mnew) : 0.f;
        Ps[r0 + i][c0 + j] = p;
        psum += p;
      }
      #pragma unroll
      for (int m = 8; m >= 1; m >>= 1) psum += __shfl_xor(psum, m, 64);
      if (stx == 0) {
        m_s[r0 + i] = mnew;
        l_s[r0 + i] = l_s[r0 + i] * al + psum;
        al_s[r0 + i] = al;
      }
    }
    __syncthreads();
    #pragma unroll
    for (int i = 0; i < 2; i++) {
      const float al = al_s[r0 + i];
      #pragma unroll
      for (int j = 0; j < 8; j++) O[i][j] *= al;
    }
    for (int kk = 0; kk < 32; kk++) {
      float p0 = Ps[r0][kk], p1 = Ps[r0 + 1][kk];
      #pragma unroll
      for (int j = 0; j < 8; j++) {
        float vv = Vs[kk][stx * 8 + j];
        O[0][j] += p0 * vv; O[1][j] += p1 * vv;
      }
    }
    __syncthreads();
  }
  #pragma unroll
  for (int i = 0; i < 2; i++) {
    const float inv = 1.0f / l_s[r0 + i];
    #pragma unroll
    for (int j = 0; j < 8; j++)
      enc[((long)(bb * T_ + q0 + r0 + i) * NH + n) * HD + stx * 8 + j] = O[i][j] * inv;
  }
}

extern "C" void kernel_launch(void* const* d_in, const int* in_sizes, int n_in,
                              void* d_out, int out_size, void* d_ws, size_t ws_size,
                              hipStream_t stream) {
  (void)in_sizes; (void)n_in; (void)out_size; (void)ws_size;
  const float* x      = (const float*)d_in[0];
  const int*   segp   = (const int*)d_in[1];
  // d_in[2] = attn_mask (causal tril) — computed analytically, unused
  const float* qk_    = (const float*)d_in[3];
  const float* kvk    = (const float*)d_in[4];
  const float* ok_    = (const float*)d_in[5];
  const float* gw     = (const float*)d_in[6];
  const float* uw     = (const float*)d_in[7];
  const float* dw     = (const float*)d_in[8];
  const float* pre_a  = (const float*)d_in[9];
  const float* post_a = (const float*)d_in[10];
  const float* pre_f  = (const float*)d_in[11];
  const float* post_f = (const float*)d_in[12];
  const float* qns    = (const float*)d_in[13];
  const float* kns    = (const float*)d_in[14];
  float* out = (float*)d_out;

  float* ws = (float*)d_ws;
  const long M1 = 1024 * 1024;
  float* h    = ws;             // [BT,D]      pre-attn normed; later reused for down-proj out
  float* qb   = ws + 4  * M1;   // [BT,NH,HD]
  float* kb   = ws + 8  * M1;   // [BT,KH,HD]
  float* vb   = ws + 10 * M1;   // [BT,KH,HD]
  float* enc  = ws + 12 * M1;   // [BT,NH,HD]
  float* araw = ws + 16 * M1;   // [BT,D] o-proj raw
  float* attn = ws + 20 * M1;   // [BT,D] post-attn-norm + residual (persists)
  float* h2   = ws + 24 * M1;   // [BT,D]
  float* act  = ws + 28 * M1;   // [BT,HID]
  float* dn   = h;

  // 1. pre-attn RMSNorm
  rmsnorm_k<<<BT_, 256, 0, stream>>>(x, pre_a, nullptr, h);
  // 2. Q/K/V projections (batched per head over grid.z)
  gemm_f32<<<dim3(32, 1, NH), 256, 0, stream>>>(h, D_, 0L, qk_, HD, (long)D_ * HD,
                                                qb, NH * HD, (long)HD, D_);
  gemm_f32<<<dim3(32, 1, KH), 256, 0, stream>>>(h, D_, 0L, kvk, HD, (long)D_ * HD,
                                                kb, KH * HD, (long)HD, D_);
  gemm_f32<<<dim3(32, 1, KH), 256, 0, stream>>>(h, D_, 0L, kvk + (long)KH * D_ * HD, HD,
                                                (long)D_ * HD, vb, KH * HD, (long)HD, D_);
  // 3. QK-norm + RoPE + q scaling
  qk_rope_k<<<dim3(BT_, NH + KH), 128, 0, stream>>>(qb, kb, qns, kns, segp);
  // 4. attention
  attn_k<<<dim3(T_ / 32, NH, B_), 256, 0, stream>>>(qb, kb, vb, enc);
  // 5. output projection
  gemm_f32<<<dim3(32, 16, 1), 256, 0, stream>>>(enc, NH * HD, 0L, ok_, D_, 0L,
                                                araw, D_, 0L, NH * HD);
  // 6. post-attn norm + residual(x)
  rmsnorm_k<<<BT_, 256, 0, stream>>>(araw, post_a, x, attn);
  // 7. pre-ffw norm
  rmsnorm_k<<<BT_, 256, 0, stream>>>(attn, pre_f, nullptr, h2);
  // 8. gate/up GEMMs + GELU*up epilogue
  gemm_gateup<<<dim3(32, 64, 1), 256, 0, stream>>>(h2, gw, uw, act);
  // 9. down projection
  gemm_f32<<<dim3(32, 16, 1), 256, 0, stream>>>(act, HID_, 0L, dw, D_, 0L, dn, D_, 0L, HID_);
  // 10. post-ffw norm + residual(attn)
  rmsnorm_k<<<BT_, 256, 0, stream>>>(dn, post_f, attn, out);
}

// Round 4
// 1284.258 us; speedup vs baseline: 3.4492x; 3.4492x over previous
//
#include <hip/hip_runtime.h>
#include <hip/hip_bf16.h>
#include <cmath>

#define B_ 2
#define T_ 1024
#define D_ 2048
#define NH 16
#define KH 8
#define HD 128
#define HID_ 8192
#define BT_ (B_*T_)
#define WIN 512

typedef __hip_bfloat16 bf16;
typedef __bf16 bf16x8 __attribute__((ext_vector_type(8)));
typedef float f32x4 __attribute__((ext_vector_type(4)));

__device__ __forceinline__ float wave_sum(float v) {
  #pragma unroll
  for (int o = 32; o > 0; o >>= 1) v += __shfl_down(v, o, 64);
  return v;
}

// ---------- transpose + fp32->bf16 convert: dst[c][r] = src[r][c], batched ----------
__global__ __launch_bounds__(256) void tconv(
    const float* __restrict__ src, bf16* __restrict__ dst,
    int R, int C, long sStride, long dStride)
{
  src += (long)blockIdx.z * sStride;
  dst += (long)blockIdx.z * dStride;
  __shared__ float t[32][33];
  const int c0 = blockIdx.x * 32, r0 = blockIdx.y * 32;
  const int tx = threadIdx.x & 31, ty = threadIdx.x >> 5;   // 32 x 8
  #pragma unroll
  for (int i = 0; i < 32; i += 8)
    t[ty + i][tx] = src[(long)(r0 + ty + i) * C + c0 + tx];
  __syncthreads();
  #pragma unroll
  for (int i = 0; i < 32; i += 8)
    dst[(long)(c0 + ty + i) * R + r0 + tx] = __float2bfloat16(t[tx][ty + i]);
}

// ---------- RMSNorm over D; templated output type and residual ----------
template <bool TOBF, bool RES>
__global__ __launch_bounds__(256) void rmsnorm_t(
    const float* __restrict__ in, const float* __restrict__ scale,
    const float* __restrict__ res, void* __restrict__ outv)
{
  const long row = blockIdx.x;
  const float* x = in + row * D_;
  float ss = 0.f;
  for (int c = threadIdx.x; c < D_; c += 256) { float v = x[c]; ss += v * v; }
  ss = wave_sum(ss);
  __shared__ float red[4];
  if ((threadIdx.x & 63) == 0) red[threadIdx.x >> 6] = ss;
  __syncthreads();
  const float tot = red[0] + red[1] + red[2] + red[3];
  const float rs = rsqrtf(tot * (1.0f / D_) + 1e-6f);
  for (int c = threadIdx.x; c < D_; c += 256) {
    float v = x[c] * rs * (1.0f + scale[c]);
    if constexpr (RES) v += res[row * D_ + c];
    if constexpr (TOBF) ((bf16*)outv)[row * D_ + c] = __float2bfloat16(v);
    else                ((float*)outv)[row * D_ + c] = v;
  }
}

// ---------- bf16 MFMA GEMM: C[M,N](f32) = A[M,K] @ Bt[N,K]^T, reg-staged ----------
__global__ __launch_bounds__(256) void mm_bf16(
    const bf16* __restrict__ A, const bf16* __restrict__ Bt,
    float* __restrict__ C, int K, int N)
{
  __shared__ __align__(16) bf16 As[128 * 32];
  __shared__ __align__(16) bf16 Bs[128 * 32];
  const int tid = threadIdx.x;
  const long m0 = (long)blockIdx.x * 128, n0 = (long)blockIdx.y * 128;
  const int lane = tid & 63, wid = tid >> 6;
  const int wr = (wid >> 1) * 64, wc = (wid & 1) * 64;
  const int sr = tid >> 2, sc = (tid & 3) * 8;
  const bf16* ga0 = A + (m0 + sr) * (long)K + sc;
  const bf16* ga1 = ga0 + 64 * (long)K;
  const bf16* gb0 = Bt + (n0 + sr) * (long)K + sc;
  const bf16* gb1 = gb0 + 64 * (long)K;
  bf16x8* la0 = (bf16x8*)(As + tid * 8);
  bf16x8* la1 = (bf16x8*)(As + (tid + 256) * 8);
  bf16x8* lb0 = (bf16x8*)(Bs + tid * 8);
  bf16x8* lb1 = (bf16x8*)(Bs + (tid + 256) * 8);
  const int fr = lane & 15, fk = (lane >> 4) * 8;
  f32x4 acc[4][4] = {};
  for (int k0 = 0; k0 < K; k0 += 32) {
    bf16x8 ra0 = *(const bf16x8*)(ga0 + k0);
    bf16x8 ra1 = *(const bf16x8*)(ga1 + k0);
    bf16x8 rb0 = *(const bf16x8*)(gb0 + k0);
    bf16x8 rb1 = *(const bf16x8*)(gb1 + k0);
    *la0 = ra0; *la1 = ra1; *lb0 = rb0; *lb1 = rb1;
    __syncthreads();
    bf16x8 af[4], bfv[4];
    #pragma unroll
    for (int i = 0; i < 4; i++) {
      af[i]  = *(const bf16x8*)&As[(wr + i * 16 + fr) * 32 + fk];
      bfv[i] = *(const bf16x8*)&Bs[(wc + i * 16 + fr) * 32 + fk];
    }
    #pragma unroll
    for (int i = 0; i < 4; i++)
      #pragma unroll
      for (int j = 0; j < 4; j++)
        acc[i][j] = __builtin_amdgcn_mfma_f32_16x16x32_bf16(af[i], bfv[j], acc[i][j], 0, 0, 0);
    __syncthreads();
  }
  const int cr = (lane >> 4) * 4, cc = lane & 15;
  #pragma unroll
  for (int i = 0; i < 4; i++)
    #pragma unroll
    for (int j = 0; j < 4; j++)
      #pragma unroll
      for (int q = 0; q < 4; q++)
        C[(m0 + wr + i * 16 + cr + q) * (long)N + n0 + wc + j * 16 + cc] = acc[i][j][q];
}

// ---------- fused gate/up GEMMs + GELU*up epilogue, bf16 out, reg-staged ----------
__global__ __launch_bounds__(256) void mm_gateup(
    const bf16* __restrict__ A, const bf16* __restrict__ Bg,
    const bf16* __restrict__ Bu, bf16* __restrict__ Cb)
{
  __shared__ __align__(16) bf16 As[128 * 32];
  __shared__ __align__(16) bf16 Bs[128 * 32];
  const int tid = threadIdx.x;
  const long m0 = (long)blockIdx.x * 128, n0 = (long)blockIdx.y * 128;
  const int lane = tid & 63, wid = tid >> 6;
  const int wr = (wid >> 1) * 64, wc = (wid & 1) * 64;
  const int sr = tid >> 2, sc = (tid & 3) * 8;
  const bf16* ga0 = A + (m0 + sr) * (long)D_ + sc;
  const bf16* ga1 = ga0 + 64 * (long)D_;
  bf16x8* la0 = (bf16x8*)(As + tid * 8);
  bf16x8* la1 = (bf16x8*)(As + (tid + 256) * 8);
  bf16x8* lb0 = (bf16x8*)(Bs + tid * 8);
  bf16x8* lb1 = (bf16x8*)(Bs + (tid + 256) * 8);
  const int fr = lane & 15, fk = (lane >> 4) * 8;
  f32x4 accg[4][4] = {}, accu[4][4] = {};

#define GU_PASS(BPTR, ACC) \
  { const bf16* gb0 = BPTR + (n0 + sr) * (long)D_ + sc; \
    const bf16* gb1 = gb0 + 64 * (long)D_; \
    for (int k0 = 0; k0 < D_; k0 += 32) { \
      bf16x8 ra0 = *(const bf16x8*)(ga0 + k0); \
      bf16x8 ra1 = *(const bf16x8*)(ga1 + k0); \
      bf16x8 rb0 = *(const bf16x8*)(gb0 + k0); \
      bf16x8 rb1 = *(const bf16x8*)(gb1 + k0); \
      *la0 = ra0; *la1 = ra1; *lb0 = rb0; *lb1 = rb1; \
      __syncthreads(); \
      bf16x8 af[4], bfv[4]; \
      _Pragma("unroll") for (int i = 0; i < 4; i++) { \
        af[i]  = *(const bf16x8*)&As[(wr + i * 16 + fr) * 32 + fk]; \
        bfv[i] = *(const bf16x8*)&Bs[(wc + i * 16 + fr) * 32 + fk]; } \
      _Pragma("unroll") for (int i = 0; i < 4; i++) \
        _Pragma("unroll") for (int j = 0; j < 4; j++) \
          ACC[i][j] = __builtin_amdgcn_mfma_f32_16x16x32_bf16(af[i], bfv[j], ACC[i][j], 0, 0, 0); \
      __syncthreads(); \
    } }

  GU_PASS(Bg, accg)
  GU_PASS(Bu, accu)
#undef GU_PASS

  const int cr = (lane >> 4) * 4, cc = lane & 15;
  #pragma unroll
  for (int i = 0; i < 4; i++)
    #pragma unroll
    for (int j = 0; j < 4; j++)
      #pragma unroll
      for (int q = 0; q < 4; q++) {
        float g = accg[i][j][q], u = accu[i][j][q];
        float t = tanhf(0.7978845608028654f * (g + 0.044715f * g * g * g));
        Cb[(m0 + wr + i * 16 + cr + q) * (long)HID_ + n0 + wc + j * 16 + cc] =
            __float2bfloat16(0.5f * g * (1.0f + t) * u);
      }
}

// ---------- per-head RMSNorm + RoPE (+ q scaling) in the fused qkv buffer ----------
__global__ __launch_bounds__(128) void qk_rope_k(
    float* __restrict__ qkvb, const float* __restrict__ qsc,
    const float* __restrict__ ksc, const int* __restrict__ segpos)
{
  const int row = blockIdx.x, hs = blockIdx.y;   // hs: 0..15 q heads, 16..23 k heads
  const bool isq = hs < NH;
  float* base = qkvb + (long)row * 4096 + (isq ? hs * HD : 2048 + (hs - NH) * HD);
  const float* sc = isq ? qsc : ksc;
  const int j = threadIdx.x;
  float v = base[j];
  float ss = v * v;
  #pragma unroll
  for (int o = 32; o > 0; o >>= 1) ss += __shfl_down(ss, o, 64);
  __shared__ float red[2];
  if ((j & 63) == 0) red[j >> 6] = ss;
  __syncthreads();
  const float rs = rsqrtf((red[0] + red[1]) * (1.0f / HD) + 1e-6f);
  __shared__ float tmp[HD];
  tmp[j] = v * rs * (1.0f + sc[j]);
  __syncthreads();
  const int jj = j & 63;
  const float ts = powf(10000.0f, (float)jj * (1.0f / 64.0f));
  const float ang = (float)segpos[row] / ts;
  float sn, cs;
  sincosf(ang, &sn, &cs);
  const float fi = tmp[jj], se = tmp[jj + 64];
  float outv = (j < 64) ? (fi * cs - se * sn) : (se * cs + fi * sn);
  if (isq) outv *= 0.08838834764831845f;   // 128^-0.5
  base[j] = outv;
}

// ---------- flash-style fp32 attention, causal + window, soft-cap; bf16 enc out ----------
__global__ __launch_bounds__(256) void attn_k(
    const float* __restrict__ qkvb, bf16* __restrict__ enc)
{
  const int qt = blockIdx.x, n = blockIdx.y, bb = blockIdx.z;
  const int kh = n >> 1;            // G = NH/KH = 2
  const int q0 = qt * 32;
  __shared__ float Qs[32][HD + 1];
  __shared__ float Ks[32][HD + 1];
  __shared__ float Vs[32][HD + 1];
  __shared__ float Ps[32][33];
  __shared__ float m_s[32], l_s[32], al_s[32];
  const int tid = threadIdx.x;
  for (int idx = tid; idx < 32 * HD; idx += 256) {
    int r = idx >> 7, c = idx & (HD - 1);
    Qs[r][c] = qkvb[(long)(bb * T_ + q0 + r) * 4096 + n * HD + c];
  }
  if (tid < 32) { m_s[tid] = -1e30f; l_s[tid] = 0.f; }
  float O[2][8] = {};
  const int sty = tid >> 4, stx = tid & 15;
  const int r0 = sty * 2, c0 = stx * 2;
  const int kt_lo = (q0 >= WIN) ? (q0 - (WIN - 1)) / 32 : 0;
  for (int kt = kt_lo; kt <= qt; kt++) {
    const int k0 = kt * 32;
    for (int idx = tid; idx < 32 * HD; idx += 256) {
      int r = idx >> 7, c = idx & (HD - 1);
      long g = (long)(bb * T_ + k0 + r) * 4096 + kh * HD + c;
      Ks[r][c] = qkvb[g + 2048];
      Vs[r][c] = qkvb[g + 3072];
    }
    __syncthreads();
    float s[2][2] = {};
    for (int kk = 0; kk < HD; kk++) {
      float a0 = Qs[r0][kk], a1 = Qs[r0 + 1][kk];
      float b0 = Ks[c0][kk], b1 = Ks[c0 + 1][kk];
      s[0][0] += a0 * b0; s[0][1] += a0 * b1;
      s[1][0] += a1 * b0; s[1][1] += a1 * b1;
    }
    #pragma unroll
    for (int i = 0; i < 2; i++) {
      const int qp = q0 + r0 + i;
      float sv[2]; bool vld[2];
      float rm = -1e30f;
      #pragma unroll
      for (int j = 0; j < 2; j++) {
        const int kp = k0 + c0 + j;
        float t = tanhf(s[i][j] * (1.0f / 50.0f)) * 50.0f;   // soft-cap
        bool ok = (kp <= qp) && (kp > qp - WIN);
        sv[j] = t; vld[j] = ok;
        if (ok) rm = fmaxf(rm, t);
      }
      #pragma unroll
      for (int m = 8; m >= 1; m >>= 1) rm = fmaxf(rm, __shfl_xor(rm, m, 64));
      const float mold = m_s[r0 + i];
      const float mnew = fmaxf(mold, rm);
      const float al = expf(mold - mnew);
      float psum = 0.f;
      #pragma unroll
      for (int j = 0; j < 2; j++) {
        float p = vld[j] ? expf(sv[j] - mnew) : 0.f;
        Ps[r0 + i][c0 + j] = p;
        psum += p;
      }
      #pragma unroll
      for (int m = 8; m >= 1; m >>= 1) psum += __shfl_xor(psum, m, 64);
      if (stx == 0) {
        m_s[r0 + i] = mnew;
        l_s[r0 + i] = l_s[r0 + i] * al + psum;
        al_s[r0 + i] = al;
      }
    }
    __syncthreads();
    #pragma unroll
    for (int i = 0; i < 2; i++) {
      const float al = al_s[r0 + i];
      #pragma unroll
      for (int j = 0; j < 8; j++) O[i][j] *= al;
    }
    for (int kk = 0; kk < 32; kk++) {
      float p0 = Ps[r0][kk], p1 = Ps[r0 + 1][kk];
      #pragma unroll
      for (int j = 0; j < 8; j++) {
        float vv = Vs[kk][stx * 8 + j];
        O[0][j] += p0 * vv; O[1][j] += p1 * vv;
      }
    }
    __syncthreads();
  }
  #pragma unroll
  for (int i = 0; i < 2; i++) {
    const float inv = 1.0f / l_s[r0 + i];
    #pragma unroll
    for (int j = 0; j < 8; j++)
      enc[(long)(bb * T_ + q0 + r0 + i) * 2048 + n * HD + stx * 8 + j] =
          __float2bfloat16(O[i][j] * inv);
  }
}

extern "C" void kernel_launch(void* const* d_in, const int* in_sizes, int n_in,
                              void* d_out, int out_size, void* d_ws, size_t ws_size,
                              hipStream_t stream) {
  (void)in_sizes; (void)n_in; (void)out_size; (void)ws_size;
  const float* x      = (const float*)d_in[0];
  const int*   segp   = (const int*)d_in[1];
  // d_in[2] = attn_mask (causal tril) — computed analytically, unused
  const float* qk_    = (const float*)d_in[3];
  const float* kvk    = (const float*)d_in[4];
  const float* ok_    = (const float*)d_in[5];
  const float* gw     = (const float*)d_in[6];
  const float* uw     = (const float*)d_in[7];
  const float* dw     = (const float*)d_in[8];
  const float* pre_a  = (const float*)d_in[9];
  const float* post_a = (const float*)d_in[10];
  const float* pre_f  = (const float*)d_in[11];
  const float* post_f = (const float*)d_in[12];
  const float* qns    = (const float*)d_in[13];
  const float* kns    = (const float*)d_in[14];
  float* out = (float*)d_out;

  // ---- workspace plan: max 176 MiB (R1's proven-safe footprint) ----
  char* wsb = (char*)d_ws;
  bf16*  WQKV = (bf16*)(wsb);                     // [  0, 16) [4096,2048] bf16
  bf16*  WO   = (bf16*)(wsb + (16L  << 20));      // [ 16, 24) [2048,2048] bf16
  bf16*  WG   = (bf16*)(wsb + (24L  << 20));      // [ 24, 56) [8192,2048] bf16
  bf16*  WU   = (bf16*)(wsb + (56L  << 20));      // [ 56, 88) [8192,2048] bf16
  bf16*  WD   = (bf16*)(wsb + (88L  << 20));      // [ 88,120) [2048,8192] bf16
  bf16*  HB   = (bf16*)(wsb + (120L << 20));      // [120,128) h -> ENC -> H2 (bf16)
  float* QKVB = (float*)(wsb + (128L << 20));     // [128,160) f32; then ARAW; then ACT
  float* ATTN = (float*)(wsb + (160L << 20));     // [160,176) f32, live to end
  bf16*  ENC  = HB;                               // after h consumed
  bf16*  H2   = HB;                               // after ENC consumed
  float* ARAW = QKVB;                             // [128,144) after QKVB consumed
  bf16*  ACT  = (bf16*)QKVB;                      // [128,160) after ARAW consumed
  float* DN   = (float*)(wsb + (24L << 20));      // reuses WG region (dead after gateup;
                                                  // tconv rewrites WG next launch)

  // --- weight transpose + bf16 convert (every launch; deterministic) ---
  tconv<<<dim3(HD / 32, D_ / 32, NH), 256, 0, stream>>>(
      qk_, WQKV, D_, HD, (long)D_ * HD, (long)HD * D_);
  tconv<<<dim3(HD / 32, D_ / 32, KH), 256, 0, stream>>>(
      kvk, WQKV + (long)2048 * D_, D_, HD, (long)D_ * HD, (long)HD * D_);
  tconv<<<dim3(HD / 32, D_ / 32, KH), 256, 0, stream>>>(
      kvk + (long)KH * D_ * HD, WQKV + (long)3072 * D_, D_, HD, (long)D_ * HD, (long)HD * D_);
  tconv<<<dim3(D_ / 32, D_ / 32, 1), 256, 0, stream>>>(ok_, WO, D_, D_, 0, 0);
  tconv<<<dim3(HID_ / 32, D_ / 32, 1), 256, 0, stream>>>(gw, WG, D_, HID_, 0, 0);
  tconv<<<dim3(HID_ / 32, D_ / 32, 1), 256, 0, stream>>>(uw, WU, D_, HID_, 0, 0);
  tconv<<<dim3(D_ / 32, HID_ / 32, 1), 256, 0, stream>>>(dw, WD, HID_, D_, 0, 0);

  // --- transformer block ---
  rmsnorm_t<true,  false><<<BT_, 256, 0, stream>>>(x, pre_a, nullptr, HB);
  mm_bf16<<<dim3(BT_ / 128, 4096 / 128), 256, 0, stream>>>(HB, WQKV, QKVB, D_, 4096);
  qk_rope_k<<<dim3(BT_, NH + KH), 128, 0, stream>>>(QKVB, qns, kns, segp);
  attn_k<<<dim3(T_ / 32, NH, B_), 256, 0, stream>>>(QKVB, ENC);
  mm_bf16<<<dim3(BT_ / 128, D_ / 128), 256, 0, stream>>>(ENC, WO, ARAW, D_, D_);
  rmsnorm_t<false, true ><<<BT_, 256, 0, stream>>>(ARAW, post_a, x, ATTN);
  rmsnorm_t<true,  false><<<BT_, 256, 0, stream>>>(ATTN, pre_f, nullptr, H2);
  mm_gateup<<<dim3(BT_ / 128, HID_ / 128), 256, 0, stream>>>(H2, WG, WU, ACT);
  mm_bf16<<<dim3(BT_ / 128, D_ / 128), 256, 0, stream>>>(ACT, WD, DN, HID_, D_);
  rmsnorm_t<false, true ><<<BT_, 256, 0, stream>>>(DN, post_f, ATTN, out);
}

// Round 5
// 836.723 us; speedup vs baseline: 5.2941x; 1.5349x over previous
//
#include <hip/hip_runtime.h>
#include <hip/hip_bf16.h>
#include <cmath>

#define B_ 2
#define T_ 1024
#define D_ 2048
#define NH 16
#define KH 8
#define HD 128
#define HID_ 8192
#define BT_ (B_*T_)
#define WIN 512

typedef __hip_bfloat16 bf16;
typedef __bf16 bf16x8 __attribute__((ext_vector_type(8)));
typedef float f32x4 __attribute__((ext_vector_type(4)));

__device__ __forceinline__ float wave_sum(float v) {
  #pragma unroll
  for (int o = 32; o > 0; o >>= 1) v += __shfl_down(v, o, 64);
  return v;
}

// ---------- transpose + fp32->bf16 convert: dst[c][r] = src[r][c], batched ----------
__global__ __launch_bounds__(256) void tconv(
    const float* __restrict__ src, bf16* __restrict__ dst,
    int R, int C, long sStride, long dStride)
{
  src += (long)blockIdx.z * sStride;
  dst += (long)blockIdx.z * dStride;
  __shared__ float t[32][33];
  const int c0 = blockIdx.x * 32, r0 = blockIdx.y * 32;
  const int tx = threadIdx.x & 31, ty = threadIdx.x >> 5;   // 32 x 8
  #pragma unroll
  for (int i = 0; i < 32; i += 8)
    t[ty + i][tx] = src[(long)(r0 + ty + i) * C + c0 + tx];
  __syncthreads();
  #pragma unroll
  for (int i = 0; i < 32; i += 8)
    dst[(long)(c0 + ty + i) * R + r0 + tx] = __float2bfloat16(t[tx][ty + i]);
}

// ---------- RMSNorm over D; templated output type and residual ----------
template <bool TOBF, bool RES>
__global__ __launch_bounds__(256) void rmsnorm_t(
    const float* __restrict__ in, const float* __restrict__ scale,
    const float* __restrict__ res, void* __restrict__ outv)
{
  const long row = blockIdx.x;
  const float* x = in + row * D_;
  float ss = 0.f;
  for (int c = threadIdx.x; c < D_; c += 256) { float v = x[c]; ss += v * v; }
  ss = wave_sum(ss);
  __shared__ float red[4];
  if ((threadIdx.x & 63) == 0) red[threadIdx.x >> 6] = ss;
  __syncthreads();
  const float tot = red[0] + red[1] + red[2] + red[3];
  const float rs = rsqrtf(tot * (1.0f / D_) + 1e-6f);
  for (int c = threadIdx.x; c < D_; c += 256) {
    float v = x[c] * rs * (1.0f + scale[c]);
    if constexpr (RES) v += res[row * D_ + c];
    if constexpr (TOBF) ((bf16*)outv)[row * D_ + c] = __float2bfloat16(v);
    else                ((float*)outv)[row * D_ + c] = v;
  }
}

// ---------- bf16 MFMA GEMM: C[M,N](f32) = A[M,K] @ Bt[N,K]^T, reg-staged ----------
__global__ __launch_bounds__(256) void mm_bf16(
    const bf16* __restrict__ A, const bf16* __restrict__ Bt,
    float* __restrict__ C, int K, int N)
{
  __shared__ __align__(16) bf16 As[128 * 32];
  __shared__ __align__(16) bf16 Bs[128 * 32];
  const int tid = threadIdx.x;
  const long m0 = (long)blockIdx.x * 128, n0 = (long)blockIdx.y * 128;
  const int lane = tid & 63, wid = tid >> 6;
  const int wr = (wid >> 1) * 64, wc = (wid & 1) * 64;
  const int sr = tid >> 2, sc = (tid & 3) * 8;
  const bf16* ga0 = A + (m0 + sr) * (long)K + sc;
  const bf16* ga1 = ga0 + 64 * (long)K;
  const bf16* gb0 = Bt + (n0 + sr) * (long)K + sc;
  const bf16* gb1 = gb0 + 64 * (long)K;
  bf16x8* la0 = (bf16x8*)(As + tid * 8);
  bf16x8* la1 = (bf16x8*)(As + (tid + 256) * 8);
  bf16x8* lb0 = (bf16x8*)(Bs + tid * 8);
  bf16x8* lb1 = (bf16x8*)(Bs + (tid + 256) * 8);
  const int fr = lane & 15, fk = (lane >> 4) * 8;
  f32x4 acc[4][4] = {};
  for (int k0 = 0; k0 < K; k0 += 32) {
    bf16x8 ra0 = *(const bf16x8*)(ga0 + k0);
    bf16x8 ra1 = *(const bf16x8*)(ga1 + k0);
    bf16x8 rb0 = *(const bf16x8*)(gb0 + k0);
    bf16x8 rb1 = *(const bf16x8*)(gb1 + k0);
    *la0 = ra0; *la1 = ra1; *lb0 = rb0; *lb1 = rb1;
    __syncthreads();
    bf16x8 af[4], bfv[4];
    #pragma unroll
    for (int i = 0; i < 4; i++) {
      af[i]  = *(const bf16x8*)&As[(wr + i * 16 + fr) * 32 + fk];
      bfv[i] = *(const bf16x8*)&Bs[(wc + i * 16 + fr) * 32 + fk];
    }
    #pragma unroll
    for (int i = 0; i < 4; i++)
      #pragma unroll
      for (int j = 0; j < 4; j++)
        acc[i][j] = __builtin_amdgcn_mfma_f32_16x16x32_bf16(af[i], bfv[j], acc[i][j], 0, 0, 0);
    __syncthreads();
  }
  const int cr = (lane >> 4) * 4, cc = lane & 15;
  #pragma unroll
  for (int i = 0; i < 4; i++)
    #pragma unroll
    for (int j = 0; j < 4; j++)
      #pragma unroll
      for (int q = 0; q < 4; q++)
        C[(m0 + wr + i * 16 + cr + q) * (long)N + n0 + wc + j * 16 + cc] = acc[i][j][q];
}

// ---------- fused gate/up GEMMs + GELU*up epilogue, bf16 out, reg-staged ----------
__global__ __launch_bounds__(256) void mm_gateup(
    const bf16* __restrict__ A, const bf16* __restrict__ Bg,
    const bf16* __restrict__ Bu, bf16* __restrict__ Cb)
{
  __shared__ __align__(16) bf16 As[128 * 32];
  __shared__ __align__(16) bf16 Bs[128 * 32];
  const int tid = threadIdx.x;
  const long m0 = (long)blockIdx.x * 128, n0 = (long)blockIdx.y * 128;
  const int lane = tid & 63, wid = tid >> 6;
  const int wr = (wid >> 1) * 64, wc = (wid & 1) * 64;
  const int sr = tid >> 2, sc = (tid & 3) * 8;
  const bf16* ga0 = A + (m0 + sr) * (long)D_ + sc;
  const bf16* ga1 = ga0 + 64 * (long)D_;
  bf16x8* la0 = (bf16x8*)(As + tid * 8);
  bf16x8* la1 = (bf16x8*)(As + (tid + 256) * 8);
  bf16x8* lb0 = (bf16x8*)(Bs + tid * 8);
  bf16x8* lb1 = (bf16x8*)(Bs + (tid + 256) * 8);
  const int fr = lane & 15, fk = (lane >> 4) * 8;
  f32x4 accg[4][4] = {}, accu[4][4] = {};

#define GU_PASS(BPTR, ACC) \
  { const bf16* gb0 = BPTR + (n0 + sr) * (long)D_ + sc; \
    const bf16* gb1 = gb0 + 64 * (long)D_; \
    for (int k0 = 0; k0 < D_; k0 += 32) { \
      bf16x8 ra0 = *(const bf16x8*)(ga0 + k0); \
      bf16x8 ra1 = *(const bf16x8*)(ga1 + k0); \
      bf16x8 rb0 = *(const bf16x8*)(gb0 + k0); \
      bf16x8 rb1 = *(const bf16x8*)(gb1 + k0); \
      *la0 = ra0; *la1 = ra1; *lb0 = rb0; *lb1 = rb1; \
      __syncthreads(); \
      bf16x8 af[4], bfv[4]; \
      _Pragma("unroll") for (int i = 0; i < 4; i++) { \
        af[i]  = *(const bf16x8*)&As[(wr + i * 16 + fr) * 32 + fk]; \
        bfv[i] = *(const bf16x8*)&Bs[(wc + i * 16 + fr) * 32 + fk]; } \
      _Pragma("unroll") for (int i = 0; i < 4; i++) \
        _Pragma("unroll") for (int j = 0; j < 4; j++) \
          ACC[i][j] = __builtin_amdgcn_mfma_f32_16x16x32_bf16(af[i], bfv[j], ACC[i][j], 0, 0, 0); \
      __syncthreads(); \
    } }

  GU_PASS(Bg, accg)
  GU_PASS(Bu, accu)
#undef GU_PASS

  const int cr = (lane >> 4) * 4, cc = lane & 15;
  #pragma unroll
  for (int i = 0; i < 4; i++)
    #pragma unroll
    for (int j = 0; j < 4; j++)
      #pragma unroll
      for (int q = 0; q < 4; q++) {
        float g = accg[i][j][q], u = accu[i][j][q];
        float t = tanhf(0.7978845608028654f * (g + 0.044715f * g * g * g));
        Cb[(m0 + wr + i * 16 + cr + q) * (long)HID_ + n0 + wc + j * 16 + cc] =
            __float2bfloat16(0.5f * g * (1.0f + t) * u);
      }
}

// ---------- per-head RMSNorm + RoPE (+ q scaling); fp32 in -> bf16 out ----------
// hs: 0..15 q heads (norm+rope+scale), 16..23 k heads (norm+rope), 24..31 v heads (convert)
__global__ __launch_bounds__(128) void qkv_prep(
    const float* __restrict__ qkvb, bf16* __restrict__ qkvh,
    const float* __restrict__ qsc, const float* __restrict__ ksc,
    const int* __restrict__ segpos)
{
  const int row = blockIdx.x, hs = blockIdx.y;
  const int j = threadIdx.x;
  const long base = (long)row * 4096 + hs * HD;   // q|k|v contiguous: hs*128 spans all 4096
  const float v = qkvb[base + j];
  if (hs >= NH + KH) {                            // v head: convert only
    qkvh[base + j] = __float2bfloat16(v);
    return;
  }
  const bool isq = hs < NH;
  const float* sc = isq ? qsc : ksc;
  float ss = v * v;
  #pragma unroll
  for (int o = 32; o > 0; o >>= 1) ss += __shfl_down(ss, o, 64);
  __shared__ float red[2];
  if ((j & 63) == 0) red[j >> 6] = ss;
  __syncthreads();
  const float rs = rsqrtf((red[0] + red[1]) * (1.0f / HD) + 1e-6f);
  __shared__ float tmp[HD];
  tmp[j] = v * rs * (1.0f + sc[j]);
  __syncthreads();
  const int jj = j & 63;
  const float ts = powf(10000.0f, (float)jj * (1.0f / 64.0f));
  const float ang = (float)segpos[row] / ts;
  float sn, cs;
  sincosf(ang, &sn, &cs);
  const float fi = tmp[jj], se = tmp[jj + 64];
  float outv = (j < 64) ? (fi * cs - se * sn) : (se * cs + fi * sn);
  if (isq) outv *= 0.08838834764831845f;   // 128^-0.5
  qkvh[base + j] = __float2bfloat16(outv);
}

// ---------- bf16 MFMA flash attention: QBLK=64 (4 waves x 16 rows), KVBLK=64 ----------
__global__ __launch_bounds__(256) void attn_mfma(
    const bf16* __restrict__ qkvh, bf16* __restrict__ enc)
{
  const int qt = blockIdx.x, n = blockIdx.y, bb = blockIdx.z;
  const int kh = n >> 1;                 // G = 2
  const int q0 = qt * 64;
  __shared__ __align__(16) bf16 Ks[64 * 128];    // [key][c], swz byte^=((key&7)<<4)
  __shared__ __align__(16) bf16 Vt[128 * 64];    // [c][key], swz byte^=((c&7)<<4)
  __shared__ __align__(16) bf16 Ps[4][16 * 64];  // per-wave [r][key], swz byte^=((r&7)<<4)
  const int tid = threadIdx.x;
  const int lane = tid & 63, w = tid >> 6;
  const int cidx = lane & 15, g4 = lane >> 4;

  // Q fragments (A-frag: row = lane&15, k = g4*8 + j), rows q0 + w*16 + cidx
  bf16x8 aq[4];
  {
    const bf16* qbase = qkvh + ((long)(bb * T_) + q0 + w * 16 + cidx) * 4096 + n * HD;
    #pragma unroll
    for (int ks = 0; ks < 4; ks++)
      aq[ks] = *(const bf16x8*)(qbase + ks * 32 + g4 * 8);
  }
  f32x4 O[8] = {};
  float mrow[4], lrow[4];
  #pragma unroll
  for (int r = 0; r < 4; r++) { mrow[r] = -1e30f; lrow[r] = 0.f; }

  const int kt_lo = (q0 > WIN) ? ((q0 - WIN + 1) >> 6) : 0;
  for (int kt = kt_lo; kt <= qt; kt++) {
    const int k0 = kt * 64;
    // ---- stage K (row-major, swizzled) ----
    {
      const int cb = tid & 15, c0 = cb * 8;
      #pragma unroll
      for (int p = 0; p < 4; p++) {
        const int s = (tid >> 4) + p * 16;
        bf16x8 kv = *(const bf16x8*)(qkvh + ((long)(bb * T_) + k0 + s) * 4096 + 2048 + kh * HD + c0);
        *(bf16x8*)((char*)Ks + (s * 256 + ((c0 * 2) ^ ((s & 7) << 4)))) = kv;
      }
    }
    // ---- stage V transposed (paired-row u32 writes, swizzled) ----
    #pragma unroll
    for (int i = 0; i < 2; i++) {
      const int tau = tid + 256 * i;
      const int kp = tau & 31, vb = tau >> 5;
      const int s = kp * 2, vc0 = vb * 8;
      const bf16* vsrc = qkvh + ((long)(bb * T_) + k0 + s) * 4096 + 3072 + kh * HD + vc0;
      bf16x8 v0 = *(const bf16x8*)(vsrc);
      bf16x8 v1 = *(const bf16x8*)(vsrc + 4096);
      #pragma unroll
      for (int j = 0; j < 8; j++) {
        const int c = vc0 + j;
        union { unsigned int u; unsigned short h[2]; } up;
        up.h[0] = ((const unsigned short*)&v0)[j];
        up.h[1] = ((const unsigned short*)&v1)[j];
        *(unsigned int*)((char*)Vt + ((c * 128 + s * 2) ^ ((c & 7) << 4))) = up.u;
      }
    }
    __syncthreads();

    // ---- QK^T: S[16][64] per wave ----
    f32x4 sacc[4];
    #pragma unroll
    for (int t = 0; t < 4; t++) sacc[t] = (f32x4){0.f, 0.f, 0.f, 0.f};
    #pragma unroll
    for (int t = 0; t < 4; t++) {
      const int key = t * 16 + cidx;
      #pragma unroll
      for (int ks = 0; ks < 4; ks++) {
        const int c = ks * 32 + g4 * 8;
        bf16x8 bk = *(const bf16x8*)((char*)Ks + ((key * 256 + c * 2) ^ ((key & 7) << 4)));
        sacc[t] = __builtin_amdgcn_mfma_f32_16x16x32_bf16(aq[ks], bk, sacc[t], 0, 0, 0);
      }
    }
    // ---- softcap + mask + online softmax (rows live in 16-lane groups) ----
    float al4[4];
    #pragma unroll
    for (int r = 0; r < 4; r++) {
      const int qp = q0 + w * 16 + g4 * 4 + r;
      const float mo = mrow[r];
      float mn = mo;
      float sv[4]; bool ok[4];
      #pragma unroll
      for (int t = 0; t < 4; t++) {
        const int kp = k0 + t * 16 + cidx;
        const float e = __expf(sacc[t][r] * 0.04f);       // e^(2s/50)
        const float scv = 50.f * (1.f - 2.f / (e + 1.f)); // 50*tanh(s/50)
        ok[t] = (kp <= qp) && (kp > qp - WIN);
        sv[t] = scv;
        if (ok[t]) mn = fmaxf(mn, scv);
      }
      #pragma unroll
      for (int m = 8; m >= 1; m >>= 1) mn = fmaxf(mn, __shfl_xor(mn, m, 64));
      const float al = __expf(mo - mn);
      float ps = 0.f;
      const int rr = g4 * 4 + r;
      #pragma unroll
      for (int t = 0; t < 4; t++) {
        const float p = ok[t] ? __expf(sv[t] - mn) : 0.f;
        ps += p;
        *(unsigned short*)((char*)&Ps[w][0] +
            ((rr * 128 + (t * 16 + cidx) * 2) ^ ((rr & 7) << 4))) =
            __builtin_bit_cast(unsigned short, __float2bfloat16(p));
      }
      #pragma unroll
      for (int m = 8; m >= 1; m >>= 1) ps += __shfl_xor(ps, m, 64);
      mrow[r] = mn; lrow[r] = lrow[r] * al + ps; al4[r] = al;
    }
    // rescale O
    #pragma unroll
    for (int ct = 0; ct < 8; ct++)
      #pragma unroll
      for (int r = 0; r < 4; r++) O[ct][r] *= al4[r];
    // ---- PV: O[16][128] += P[16][64] @ V[64][128] ----
    bf16x8 pa[2];
    #pragma unroll
    for (int ks = 0; ks < 2; ks++) {
      const int s = ks * 32 + g4 * 8;
      pa[ks] = *(const bf16x8*)((char*)&Ps[w][0] + ((cidx * 128 + s * 2) ^ ((cidx & 7) << 4)));
    }
    #pragma unroll
    for (int ct = 0; ct < 8; ct++) {
      const int c = ct * 16 + cidx;
      #pragma unroll
      for (int ks = 0; ks < 2; ks++) {
        const int s = ks * 32 + g4 * 8;
        bf16x8 bv = *(const bf16x8*)((char*)Vt + ((c * 128 + s * 2) ^ ((c & 7) << 4)));
        O[ct] = __builtin_amdgcn_mfma_f32_16x16x32_bf16(pa[ks], bv, O[ct], 0, 0, 0);
      }
    }
    __syncthreads();
  }
  // ---- epilogue ----
  #pragma unroll
  for (int r = 0; r < 4; r++) {
    const float inv = 1.0f / lrow[r];
    const long row = (long)(bb * T_) + q0 + w * 16 + g4 * 4 + r;
    #pragma unroll
    for (int ct = 0; ct < 8; ct++)
      enc[row * 2048 + n * HD + ct * 16 + cidx] = __float2bfloat16(O[ct][r] * inv);
  }
}

extern "C" void kernel_launch(void* const* d_in, const int* in_sizes, int n_in,
                              void* d_out, int out_size, void* d_ws, size_t ws_size,
                              hipStream_t stream) {
  (void)in_sizes; (void)n_in; (void)out_size; (void)ws_size;
  const float* x      = (const float*)d_in[0];
  const int*   segp   = (const int*)d_in[1];
  // d_in[2] = attn_mask (causal tril) — computed analytically, unused
  const float* qk_    = (const float*)d_in[3];
  const float* kvk    = (const float*)d_in[4];
  const float* ok_    = (const float*)d_in[5];
  const float* gw     = (const float*)d_in[6];
  const float* uw     = (const float*)d_in[7];
  const float* dw     = (const float*)d_in[8];
  const float* pre_a  = (const float*)d_in[9];
  const float* post_a = (const float*)d_in[10];
  const float* pre_f  = (const float*)d_in[11];
  const float* post_f = (const float*)d_in[12];
  const float* qns    = (const float*)d_in[13];
  const float* kns    = (const float*)d_in[14];
  float* out = (float*)d_out;

  // ---- workspace plan: max 176 MiB (proven-safe footprint) ----
  char* wsb = (char*)d_ws;
  bf16*  WQKV = (bf16*)(wsb);                     // [  0, 16) [4096,2048] bf16
  bf16*  WO   = (bf16*)(wsb + (16L  << 20));      // [ 16, 24) [2048,2048] bf16
  bf16*  WG   = (bf16*)(wsb + (24L  << 20));      // [ 24, 56) [8192,2048] bf16
  bf16*  WU   = (bf16*)(wsb + (56L  << 20));      // [ 56, 88) [8192,2048] bf16
  bf16*  WD   = (bf16*)(wsb + (88L  << 20));      // [ 88,120) [2048,8192] bf16
  bf16*  HB   = (bf16*)(wsb + (120L << 20));      // [120,128) h -> ENC -> H2 (bf16)
  float* QKVB = (float*)(wsb + (128L << 20));     // [128,160) f32; dead after qkv_prep
  // [160,176): QKVH bf16 (live qkv_prep..attn), then ATTN f32 (live post-attn..end)
  bf16*  QKVH = (bf16*)(wsb + (160L << 20));
  float* ATTN = (float*)(wsb + (160L << 20));
  bf16*  ENC  = HB;
  bf16*  H2   = HB;
  float* ARAW = QKVB;                             // [128,144)
  bf16*  ACT  = (bf16*)QKVB;                      // [128,160)
  float* DN   = (float*)(wsb + (24L << 20));      // reuses WG region (dead after gateup)

  // --- weight transpose + bf16 convert (every launch; deterministic) ---
  tconv<<<dim3(HD / 32, D_ / 32, NH), 256, 0, stream>>>(
      qk_, WQKV, D_, HD, (long)D_ * HD, (long)HD * D_);
  tconv<<<dim3(HD / 32, D_ / 32, KH), 256, 0, stream>>>(
      kvk, WQKV + (long)2048 * D_, D_, HD, (long)D_ * HD, (long)HD * D_);
  tconv<<<dim3(HD / 32, D_ / 32, KH), 256, 0, stream>>>(
      kvk + (long)KH * D_ * HD, WQKV + (long)3072 * D_, D_, HD, (long)D_ * HD, (long)HD * D_);
  tconv<<<dim3(D_ / 32, D_ / 32, 1), 256, 0, stream>>>(ok_, WO, D_, D_, 0, 0);
  tconv<<<dim3(HID_ / 32, D_ / 32, 1), 256, 0, stream>>>(gw, WG, D_, HID_, 0, 0);
  tconv<<<dim3(HID_ / 32, D_ / 32, 1), 256, 0, stream>>>(uw, WU, D_, HID_, 0, 0);
  tconv<<<dim3(D_ / 32, HID_ / 32, 1), 256, 0, stream>>>(dw, WD, HID_, D_, 0, 0);

  // --- transformer block ---
  rmsnorm_t<true,  false><<<BT_, 256, 0, stream>>>(x, pre_a, nullptr, HB);
  mm_bf16<<<dim3(BT_ / 128, 4096 / 128), 256, 0, stream>>>(HB, WQKV, QKVB, D_, 4096);
  qkv_prep<<<dim3(BT_, NH + KH + KH), 128, 0, stream>>>(QKVB, QKVH, qns, kns, segp);
  attn_mfma<<<dim3(T_ / 64, NH, B_), 256, 0, stream>>>(QKVH, ENC);
  mm_bf16<<<dim3(BT_ / 128, D_ / 128), 256, 0, stream>>>(ENC, WO, ARAW, D_, D_);
  rmsnorm_t<false, true ><<<BT_, 256, 0, stream>>>(ARAW, post_a, x, ATTN);
  rmsnorm_t<true,  false><<<BT_, 256, 0, stream>>>(ATTN, pre_f, nullptr, H2);
  mm_gateup<<<dim3(BT_ / 128, HID_ / 128), 256, 0, stream>>>(H2, WG, WU, ACT);
  mm_bf16<<<dim3(BT_ / 128, D_ / 128), 256, 0, stream>>>(ACT, WD, DN, HID_, D_);
  rmsnorm_t<false, true ><<<BT_, 256, 0, stream>>>(DN, post_f, ATTN, out);
}